// Round 2
// baseline (336.057 us; speedup 1.0000x reference)
//
#include <hip/hip_runtime.h>

// RelativeSAMAttention: B=4,H=8,N=1024,DH=128. Outputs FP32: out[B,H,N,DH] ++ scores[B,H,N,N].
// Grid: 256 blocks = tile(8) * bh(32), bid = tile*32 + bh  (same bh -> same XCD for K/V L2 reuse).
// Block: 512 threads = 8 waves; wave w owns rows [w*16, w*16+16) of its 128-row n-tile.
//
// Two-pass recompute (d_out is WRITE-ONLY — no global readback hazards):
//   pass 1: S_unscaled = relu((QK^T/sqrt(128))*aw + ab), accumulate rowsums only.
//   pass 2: recompute S identically, scale by 1/detr, store fp32 scores,
//           round-trip scaled P (bf16) through LDS (C-layout -> A-layout), MFMA PV -> out.

#define NTHREADS 512
#define LD 136   // 128 + 8 pad (shorts); row stride 272B -> 16B-aligned rows, conflict-free b128 frags

typedef __attribute__((ext_vector_type(8))) short short8;
typedef __attribute__((ext_vector_type(4))) float f32x4;

__device__ __forceinline__ unsigned short f2bf(float f) {
    unsigned u = __builtin_bit_cast(unsigned, f);
    u += 0x7FFFu + ((u >> 16) & 1u);           // round-to-nearest-even
    return (unsigned short)(u >> 16);
}
__device__ __forceinline__ float softplus(float x) {   // log1p(exp(x)), stable
    return fmaxf(x, 0.f) + __logf(1.f + __expf(-fabsf(x)));
}

__global__ __launch_bounds__(NTHREADS, 2) void sam_attn(
    const float* __restrict__ q, const float* __restrict__ kp, const float* __restrict__ v,
    const float* __restrict__ c, const float* __restrict__ dqp, const float* __restrict__ dkp,
    const float* __restrict__ w_w, const float* __restrict__ b_w,
    const float* __restrict__ w_b, const float* __restrict__ b_b,
    float* __restrict__ out)
{
    __shared__ unsigned short sK[128 * LD];    // K tile [m_loc][dh], bf16
    __shared__ unsigned short sVt[128 * LD];   // pass2: V^T tile [dh][m_loc], bf16
    __shared__ unsigned short sS[128 * LD];    // start: Q staging; pass2: scaled P (C-layout rows)
    __shared__ float sdq[4][128];              // x,y,z,|.|^2 for q-rows of this n-tile
    __shared__ float sdk[4][128];              // same for k-rows of current m-tile
    __shared__ float s_red[8];
    __shared__ float s_cs;

    const int bid  = blockIdx.x;
    const int bh   = bid & 31;
    const int tile = bid >> 5;
    const int b    = bh >> 3;
    const int h    = bh & 7;
    const int n0   = tile * 128;
    const int tid  = threadIdx.x;
    const int lane = tid & 63;
    const int wave = tid >> 6;
    const int l15  = lane & 15;
    const int quad = lane >> 4;

    const float ww = w_w[h], bw = b_w[h], wb = w_b[h], bb = b_b[h];
    const float SCALE = 0.08838834764831845f;  // 1/sqrt(128)

    // ---------------- stage Q tile (fp32 -> bf16) into sS, dq geometry, cs partial ----------------
    const float* qbase = q + ((size_t)bh * 1024 + n0) * 128;
    for (int i = tid; i < 4096; i += NTHREADS) {          // 128 rows * 32 float4
        int row = i >> 5, c4 = i & 31;
        float4 t = reinterpret_cast<const float4*>(qbase)[i];
        unsigned long long pk = (unsigned long long)f2bf(t.x)
                              | ((unsigned long long)f2bf(t.y) << 16)
                              | ((unsigned long long)f2bf(t.z) << 32)
                              | ((unsigned long long)f2bf(t.w) << 48);
        *reinterpret_cast<unsigned long long*>(&sS[row * LD + c4 * 4]) = pk;
    }
    for (int i = tid; i < 128; i += NTHREADS) {
        float4 d4 = reinterpret_cast<const float4*>(dqp)[(size_t)b * 1024 + n0 + i];
        sdq[0][i] = d4.x; sdq[1][i] = d4.y; sdq[2][i] = d4.z;
        sdq[3][i] = d4.x*d4.x + d4.y*d4.y + d4.z*d4.z;
    }
    float csp = 0.f;
    for (int i = tid; i < 1024; i += NTHREADS) csp += softplus(c[(size_t)bh * 1024 + i]);
    csp += __shfl_xor(csp, 32, 64); csp += __shfl_xor(csp, 16, 64);
    csp += __shfl_xor(csp,  8, 64); csp += __shfl_xor(csp,  4, 64);
    csp += __shfl_xor(csp,  2, 64); csp += __shfl_xor(csp,  1, 64);
    if (lane == 0) s_red[wave] = csp;
    __syncthreads();
    if (tid == 0) {
        float t = 1e-9f;
        for (int i = 0; i < 8; i++) t += s_red[i];
        s_cs = t;                                          // cs + 1e-9 folded
    }

    // per-row q geometry for D-rows (n_loc = wave*16 + quad*4 + r)
    float qx[4], qy[4], qz[4], qs[4];
    #pragma unroll
    for (int r = 0; r < 4; r++) {
        int nl = wave * 16 + quad * 4 + r;
        qx[r] = sdq[0][nl]; qy[r] = sdq[1][nl]; qz[r] = sdq[2][nl]; qs[r] = sdq[3][nl];
    }
    // A fragments from Q: A[m=l15][k=quad*8+j], k-slices of 32 — sS dead afterwards
    short8 afr[4];
    {
        const unsigned short* aq = &sS[(wave * 16 + l15) * LD];
        #pragma unroll
        for (int ks = 0; ks < 4; ks++)
            afr[ks] = *reinterpret_cast<const short8*>(aq + ks * 32 + quad * 8);
    }

    const float* kbase = kp + (size_t)bh * 1024 * 128;
    const float* vbase = v + (size_t)bh * 1024 * 128;

    // ================= pass 1: row sums of unscaled S =================
    float rs4[4] = {0.f, 0.f, 0.f, 0.f};
    for (int mt = 0; mt < 8; mt++) {
        const int m0 = mt * 128;
        for (int i = tid; i < 4096; i += NTHREADS) {
            int row = i >> 5, c4 = i & 31;
            float4 t = reinterpret_cast<const float4*>(kbase + (size_t)m0 * 128)[i];
            unsigned long long pk = (unsigned long long)f2bf(t.x)
                                  | ((unsigned long long)f2bf(t.y) << 16)
                                  | ((unsigned long long)f2bf(t.z) << 32)
                                  | ((unsigned long long)f2bf(t.w) << 48);
            *reinterpret_cast<unsigned long long*>(&sK[row * LD + c4 * 4]) = pk;
        }
        for (int i = tid; i < 128; i += NTHREADS) {
            float4 d4 = reinterpret_cast<const float4*>(dkp)[(size_t)b * 1024 + m0 + i];
            sdk[0][i] = d4.x; sdk[1][i] = d4.y; sdk[2][i] = d4.z;
            sdk[3][i] = d4.x*d4.x + d4.y*d4.y + d4.z*d4.z;
        }
        __syncthreads();

        #pragma unroll
        for (int mf = 0; mf < 8; mf++) {
            f32x4 acc = {0.f, 0.f, 0.f, 0.f};
            const unsigned short* bq = &sK[(mf * 16 + l15) * LD];
            #pragma unroll
            for (int ks = 0; ks < 4; ks++) {
                short8 bfr = *reinterpret_cast<const short8*>(bq + ks * 32 + quad * 8);
                acc = __builtin_amdgcn_mfma_f32_16x16x32_bf16(afr[ks], bfr, acc, 0, 0, 0);
            }
            const int mloc = mf * 16 + l15;
            const float kx = sdk[0][mloc], ky = sdk[1][mloc], kz = sdk[2][mloc], ksq = sdk[3][mloc];
            #pragma unroll
            for (int r = 0; r < 4; r++) {
                float dist = qs[r] + ksq - 2.f * (qx[r]*kx + qy[r]*ky + qz[r]*kz);
                float aw = softplus(-(dist * ww + bw));
                float ab = dist * wb + bb;
                float val = fmaxf(acc[r] * SCALE * aw + ab, 0.f);
                rs4[r] += val;
            }
        }
        __syncthreads();   // sK reads done before next iteration's restage
    }

    // detr -> invd per D-row (xor-reduce over the 16 lanes of each quad)
    float invd[4];
    #pragma unroll
    for (int r = 0; r < 4; r++) {
        float t = rs4[r];
        t += __shfl_xor(t, 1, 64); t += __shfl_xor(t, 2, 64);
        t += __shfl_xor(t, 4, 64); t += __shfl_xor(t, 8, 64);
        invd[r] = 1.f / (t + s_cs);
    }

    // ================= pass 2: recompute, scale, store scores, fuse PV =================
    f32x4 oacc[8];
    #pragma unroll
    for (int i = 0; i < 8; i++) oacc[i] = {0.f, 0.f, 0.f, 0.f};
    float* scb = out + (size_t)4 * 8 * 1024 * 128          // scores region
               + (size_t)bh * 1024 * 1024 + (size_t)n0 * 1024;

    for (int mt = 0; mt < 8; mt++) {
        const int m0 = mt * 128;
        for (int i = tid; i < 4096; i += NTHREADS) {       // restage K (L3/L2-hot)
            int row = i >> 5, c4 = i & 31;
            float4 t = reinterpret_cast<const float4*>(kbase + (size_t)m0 * 128)[i];
            unsigned long long pk = (unsigned long long)f2bf(t.x)
                                  | ((unsigned long long)f2bf(t.y) << 16)
                                  | ((unsigned long long)f2bf(t.z) << 32)
                                  | ((unsigned long long)f2bf(t.w) << 48);
            *reinterpret_cast<unsigned long long*>(&sK[row * LD + c4 * 4]) = pk;
        }
        for (int i = tid; i < 128; i += NTHREADS) {
            float4 d4 = reinterpret_cast<const float4*>(dkp)[(size_t)b * 1024 + m0 + i];
            sdk[0][i] = d4.x; sdk[1][i] = d4.y; sdk[2][i] = d4.z;
            sdk[3][i] = d4.x*d4.x + d4.y*d4.y + d4.z*d4.z;
        }
        // stage V transposed (simple scalar form; 8-way LDS write conflicts accepted this round)
        for (int i = tid; i < 16384; i += NTHREADS) {
            int m = i >> 7, d = i & 127;
            sVt[d * LD + m] = f2bf(vbase[(size_t)(m0 + m) * 128 + d]);
        }
        __syncthreads();

        #pragma unroll
        for (int mf = 0; mf < 8; mf++) {
            f32x4 acc = {0.f, 0.f, 0.f, 0.f};
            const unsigned short* bq = &sK[(mf * 16 + l15) * LD];
            #pragma unroll
            for (int ks = 0; ks < 4; ks++) {
                short8 bfr = *reinterpret_cast<const short8*>(bq + ks * 32 + quad * 8);
                acc = __builtin_amdgcn_mfma_f32_16x16x32_bf16(afr[ks], bfr, acc, 0, 0, 0);
            }
            const int mloc = mf * 16 + l15;
            const float kx = sdk[0][mloc], ky = sdk[1][mloc], kz = sdk[2][mloc], ksq = sdk[3][mloc];
            #pragma unroll
            for (int r = 0; r < 4; r++) {
                float dist = qs[r] + ksq - 2.f * (qx[r]*kx + qy[r]*ky + qz[r]*kz);
                float aw = softplus(-(dist * ww + bw));
                float ab = dist * wb + bb;
                float val = fmaxf(acc[r] * SCALE * aw + ab, 0.f);
                float p   = val * invd[r];                 // final scaled score, fp32
                int row = wave * 16 + quad * 4 + r;
                sS[row * LD + mf * 16 + l15] = f2bf(p);    // C-layout -> LDS for PV A-frags
                scb[(size_t)row * 1024 + m0 + mf * 16 + l15] = p;   // 64B segments x4/wave
            }
        }
        __syncthreads();   // sS tile complete

        // PV: A = scaled P rows (A-layout), B = V^T rows
        short8 pfr[4];
        {
            const unsigned short* prow = &sS[(wave * 16 + l15) * LD];
            #pragma unroll
            for (int ks = 0; ks < 4; ks++)
                pfr[ks] = *reinterpret_cast<const short8*>(prow + ks * 32 + quad * 8);
        }
        #pragma unroll
        for (int df = 0; df < 8; df++) {
            const unsigned short* vq = &sVt[(df * 16 + l15) * LD];
            #pragma unroll
            for (int ks = 0; ks < 4; ks++) {
                short8 vfr = *reinterpret_cast<const short8*>(vq + ks * 32 + quad * 8);
                oacc[df] = __builtin_amdgcn_mfma_f32_16x16x32_bf16(pfr[ks], vfr, oacc[df], 0, 0, 0);
            }
        }
        __syncthreads();   // sS/sVt/sK reads done before next iteration's restage
    }

    // ---------------- epilogue: out[b,h,n,dh] fp32 (already 1/detr-scaled via P) ----------------
    float* ob = out + ((size_t)bh * 1024 + n0) * 128;
    #pragma unroll
    for (int df = 0; df < 8; df++) {
        #pragma unroll
        for (int r = 0; r < 4; r++) {
            int nl = wave * 16 + quad * 4 + r;
            ob[(size_t)nl * 128 + df * 16 + l15] = oacc[df][r];
        }
    }
}

extern "C" void kernel_launch(void* const* d_in, const int* in_sizes, int n_in,
                              void* d_out, int out_size, void* d_ws, size_t ws_size,
                              hipStream_t stream) {
    const float* q   = (const float*)d_in[0];
    const float* k   = (const float*)d_in[1];
    const float* v   = (const float*)d_in[2];
    const float* c   = (const float*)d_in[3];
    const float* dq  = (const float*)d_in[4];
    const float* dk  = (const float*)d_in[5];
    const float* w_w = (const float*)d_in[6];
    const float* b_w = (const float*)d_in[7];
    const float* w_b = (const float*)d_in[8];
    const float* b_b = (const float*)d_in[9];
    float* out = (float*)d_out;
    hipLaunchKernelGGL(sam_attn, dim3(256), dim3(NTHREADS), 0, stream,
                       q, k, v, c, dq, dk, w_w, b_w, w_b, b_b, out);
}

// Round 3
// 288.665 us; speedup vs baseline: 1.1642x; 1.1642x over previous
//
#include <hip/hip_runtime.h>

// RelativeSAMAttention: B=4,H=8,N=1024,DH=128. Outputs FP32: out[B,H,N,DH] ++ scores[B,H,N,N].
//
// Pipeline: prep_k (K->bf16 ws), prep_v (V->bf16^T ws), prep_c (cs per bh),
//   sam_main (single pass: QK^T + distmap + unscaled fp32 scores + rowsums + PV(unscaled),
//             epilogue scales O by 1/detr, writes invd to ws),
//   scale_sc (scores *= invd[row], in place).
// sam_main: 512 blocks x 512 thr, 64-row n-tiles, wave-groups A/B split m (alternate 64-tiles),
// LDS ~74KB + __launch_bounds__(512,4) -> 2 blocks/CU (16 waves/CU vs 7 in R2).

typedef __attribute__((ext_vector_type(8))) short short8;
typedef __attribute__((ext_vector_type(4))) float f32x4;

#define OUT_ELEMS 4194304ull
#define WS_K      0ull
#define WS_VT     8388608ull
#define WS_INVD   16777216ull
#define WS_CS     16908288ull

__device__ __forceinline__ unsigned short f2bf(float f) {
    unsigned u = __builtin_bit_cast(unsigned, f);
    u += 0x7FFFu + ((u >> 16) & 1u);
    return (unsigned short)(u >> 16);
}
__device__ __forceinline__ float softplus(float x) {
    return fmaxf(x, 0.f) + __logf(1.f + __expf(-fabsf(x)));
}

__global__ __launch_bounds__(256) void prep_k(const float* __restrict__ k, unsigned short* __restrict__ wsK) {
    int t = blockIdx.x * 256 + threadIdx.x;
    for (int u = t; u < 524288; u += 131072) {
        float4 a = reinterpret_cast<const float4*>(k)[u * 2];
        float4 b = reinterpret_cast<const float4*>(k)[u * 2 + 1];
        short8 o;
        o[0]=(short)f2bf(a.x); o[1]=(short)f2bf(a.y); o[2]=(short)f2bf(a.z); o[3]=(short)f2bf(a.w);
        o[4]=(short)f2bf(b.x); o[5]=(short)f2bf(b.y); o[6]=(short)f2bf(b.z); o[7]=(short)f2bf(b.w);
        reinterpret_cast<short8*>(wsK)[u] = o;
    }
}

__global__ __launch_bounds__(256) void prep_v(const float* __restrict__ v, unsigned short* __restrict__ wsVt) {
    __shared__ unsigned short sT[64 * 132];
    const int bh = blockIdx.x >> 4, m0 = (blockIdx.x & 15) * 64;
    const int tid = threadIdx.x;
    const float* src = v + ((size_t)bh * 1024 + m0) * 128;
    for (int i = tid; i < 2048; i += 256) {
        int row = i >> 5, c4 = i & 31;
        float4 t = reinterpret_cast<const float4*>(src)[i];
        unsigned long long pk = (unsigned long long)f2bf(t.x)
                              | ((unsigned long long)f2bf(t.y) << 16)
                              | ((unsigned long long)f2bf(t.z) << 32)
                              | ((unsigned long long)f2bf(t.w) << 48);
        *reinterpret_cast<unsigned long long*>(&sT[row * 132 + c4 * 4]) = pk;
    }
    __syncthreads();
    for (int u = tid; u < 2048; u += 256) {
        int dh = u >> 4, ms = u & 15;
        unsigned long long pk = (unsigned long long)sT[(ms*4+0)*132 + dh]
                              | ((unsigned long long)sT[(ms*4+1)*132 + dh] << 16)
                              | ((unsigned long long)sT[(ms*4+2)*132 + dh] << 32)
                              | ((unsigned long long)sT[(ms*4+3)*132 + dh] << 48);
        *reinterpret_cast<unsigned long long*>(&wsVt[((size_t)bh * 128 + dh) * 1024 + m0 + ms * 4]) = pk;
    }
}

__global__ __launch_bounds__(256) void prep_c(const float* __restrict__ c, float* __restrict__ wsCs) {
    __shared__ float red[4];
    const int bh = blockIdx.x, tid = threadIdx.x;
    float p = 0.f;
    for (int i = tid; i < 1024; i += 256) p += softplus(c[(size_t)bh * 1024 + i]);
    p += __shfl_xor(p, 32, 64); p += __shfl_xor(p, 16, 64); p += __shfl_xor(p, 8, 64);
    p += __shfl_xor(p,  4, 64); p += __shfl_xor(p,  2, 64); p += __shfl_xor(p, 1, 64);
    if ((tid & 63) == 0) red[tid >> 6] = p;
    __syncthreads();
    if (tid == 0) wsCs[bh] = red[0] + red[1] + red[2] + red[3] + 1e-9f;
}

__global__ __launch_bounds__(512, 4) void sam_main(
    const float* __restrict__ q, const float* __restrict__ dqp, const float* __restrict__ dkp,
    const float* __restrict__ w_w, const float* __restrict__ b_w,
    const float* __restrict__ w_b, const float* __restrict__ b_b,
    const unsigned short* __restrict__ wsK, const unsigned short* __restrict__ wsVt,
    const float* __restrict__ wsCs, float* __restrict__ wsInvd,
    float* __restrict__ out)
{
    __shared__ __align__(16) unsigned short sKall[2 * 8704];   // [g][64m][136]; aliases: Q stage, sP strips, sO merge
    __shared__ __align__(16) unsigned short sVtall[2 * 9216];  // [g][128dh][72]
    __shared__ float sdkall[2 * 256];                          // [g][4comp][64m]; aliased as rowsum buf at end
    __shared__ float s_inv[64];

    const int bid  = blockIdx.x;
    const int bh   = bid & 31;
    const int n0   = (bid >> 5) * 64;
    const int b    = bh >> 3;
    const int h    = bh & 7;
    const int tid  = threadIdx.x;
    const int lane = tid & 63;
    const int wave = tid >> 6;
    const int g    = wave >> 2;
    const int wl   = wave & 3;
    const int w16  = wl * 16;
    const int tg   = tid & 255;
    const int l15  = lane & 15;
    const int quad = lane >> 4;

    const float ww = w_w[h], bw = b_w[h], wb = w_b[h], bb = b_b[h];
    const float SCALE = 0.08838834764831845f;   // 1/sqrt(128)

    // ---- prologue: Q tile (fp32->bf16) into sKall[0..], dq geometry, cs ----
    {
        const float* qbase = q + ((size_t)bh * 1024 + n0) * 128;
        for (int i = tid; i < 2048; i += 512) {
            int row = i >> 5, c4 = i & 31;
            float4 t = reinterpret_cast<const float4*>(qbase)[i];
            unsigned long long pk = (unsigned long long)f2bf(t.x)
                                  | ((unsigned long long)f2bf(t.y) << 16)
                                  | ((unsigned long long)f2bf(t.z) << 32)
                                  | ((unsigned long long)f2bf(t.w) << 48);
            *reinterpret_cast<unsigned long long*>(&sKall[row * 136 + c4 * 4]) = pk;
        }
    }
    float qx[4], qy[4], qz[4], qs[4];
    #pragma unroll
    for (int r = 0; r < 4; r++) {
        int nl = w16 + quad * 4 + r;
        float4 d4 = reinterpret_cast<const float4*>(dqp)[(size_t)b * 1024 + n0 + nl];
        qx[r] = d4.x; qy[r] = d4.y; qz[r] = d4.z;
        qs[r] = d4.x*d4.x + d4.y*d4.y + d4.z*d4.z;
    }
    const float cs = wsCs[bh];
    __syncthreads();
    short8 afr[4];
    {
        const unsigned short* aq = &sKall[(w16 + l15) * 136];
        #pragma unroll
        for (int ks = 0; ks < 4; ks++)
            afr[ks] = *reinterpret_cast<const short8*>(aq + ks * 32 + quad * 8);
    }
    __syncthreads();   // sKall free for m-tiles

    f32x4 oacc[8];
    #pragma unroll
    for (int i = 0; i < 8; i++) oacc[i] = {0.f, 0.f, 0.f, 0.f};
    float rs[4] = {0.f, 0.f, 0.f, 0.f};
    float* scb = out + OUT_ELEMS + ((size_t)bh << 20);

    unsigned short* sKg  = sKall  + g * 8704;
    unsigned short* sVtg = sVtall + g * 9216;
    unsigned short* sP   = sKg + wl * 1152;                // 16 rows x 72 shorts, wave-private
    float* sdkg = sdkall + g * 256;

    for (int t8 = 0; t8 < 8; t8++) {
        const int m0 = (t8 * 2 + g) * 64;
        // ---- group-local staging (bf16 ws -> LDS; pure copies) ----
        for (int i = tg; i < 1024; i += 256) {             // sK: 64 rows x 16 short8
            int row = i >> 4, seg = i & 15;
            short8 d = *reinterpret_cast<const short8*>(wsK + ((size_t)bh * 1024 + m0 + row) * 128 + seg * 8);
            *reinterpret_cast<short8*>(&sKg[row * 136 + seg * 8]) = d;
        }
        for (int i = tg; i < 1024; i += 256) {             // sVt: 128 dh x 8 short8
            int dh = i >> 3, seg = i & 7;
            short8 d = *reinterpret_cast<const short8*>(wsVt + ((size_t)bh * 128 + dh) * 1024 + m0 + seg * 8);
            *reinterpret_cast<short8*>(&sVtg[dh * 72 + seg * 8]) = d;
        }
        if (tg < 64) {
            float4 d4 = reinterpret_cast<const float4*>(dkp)[(size_t)b * 1024 + m0 + tg];
            sdkg[tg] = d4.x; sdkg[64 + tg] = d4.y; sdkg[128 + tg] = d4.z;
            sdkg[192 + tg] = d4.x*d4.x + d4.y*d4.y + d4.z*d4.z;
        }
        __syncthreads();

        // ---- QK^T into registers (so sKg can be reused as sP) ----
        f32x4 cacc[4];
        #pragma unroll
        for (int mf = 0; mf < 4; mf++) {
            cacc[mf] = {0.f, 0.f, 0.f, 0.f};
            const unsigned short* bq = &sKg[(mf * 16 + l15) * 136];
            #pragma unroll
            for (int ks = 0; ks < 4; ks++) {
                short8 bfr = *reinterpret_cast<const short8*>(bq + ks * 32 + quad * 8);
                cacc[mf] = __builtin_amdgcn_mfma_f32_16x16x32_bf16(afr[ks], bfr, cacc[mf], 0, 0, 0);
            }
        }
        __syncthreads();   // all sKg reads done; region becomes sP strips

        // ---- distmap ONCE: rowsums + unscaled fp32 scores (final loc) + bf16 sP ----
        #pragma unroll
        for (int mf = 0; mf < 4; mf++) {
            const int mloc = mf * 16 + l15;
            const float kx = sdkg[mloc], ky = sdkg[64 + mloc], kz = sdkg[128 + mloc], ksq = sdkg[192 + mloc];
            #pragma unroll
            for (int r = 0; r < 4; r++) {
                float dist = qs[r] + ksq - 2.f * (qx[r]*kx + qy[r]*ky + qz[r]*kz);
                float aw = softplus(-(dist * ww + bw));
                float ab = dist * wb + bb;
                float val = fmaxf(cacc[mf][r] * SCALE * aw + ab, 0.f);
                rs[r] += val;
                sP[(quad * 4 + r) * 72 + mf * 16 + l15] = f2bf(val);
                scb[(size_t)(n0 + w16 + quad * 4 + r) * 1024 + m0 + mf * 16 + l15] = val;
            }
        }
        // ---- PV with unscaled P (wave-private sP: no barrier, lgkm only) ----
        #pragma unroll
        for (int ks2 = 0; ks2 < 2; ks2++) {
            short8 pfr = *reinterpret_cast<const short8*>(&sP[l15 * 72 + ks2 * 32 + quad * 8]);
            #pragma unroll
            for (int df = 0; df < 8; df++) {
                short8 vfr = *reinterpret_cast<const short8*>(&sVtg[(df * 16 + l15) * 72 + ks2 * 32 + quad * 8]);
                oacc[df] = __builtin_amdgcn_mfma_f32_16x16x32_bf16(pfr, vfr, oacc[df], 0, 0, 0);
            }
        }
        __syncthreads();   // sP/sVtg reads done before next restage
    }

    // ---- merge group rowsums -> invd ----
    #pragma unroll
    for (int r = 0; r < 4; r++) {
        float t = rs[r];
        t += __shfl_xor(t, 1, 64); t += __shfl_xor(t, 2, 64);
        t += __shfl_xor(t, 4, 64); t += __shfl_xor(t, 8, 64);
        if (l15 == 0) sdkall[g * 256 + w16 + quad * 4 + r] = t;   // sdk region dead
    }
    __syncthreads();
    if (tid < 64) {
        float iv = 1.f / (sdkall[tid] + sdkall[256 + tid] + cs);
        s_inv[tid] = iv;
        wsInvd[(size_t)bh * 1024 + n0 + tid] = iv;
    }
    __syncthreads();

    // ---- merge group O-partials, scale, store ----
    float* sO = reinterpret_cast<float*>(sKall) + wl * 2112;      // 16 rows x 132 floats
    if (g == 1) {
        #pragma unroll
        for (int df = 0; df < 8; df++)
            #pragma unroll
            for (int r = 0; r < 4; r++)
                sO[(quad * 4 + r) * 132 + df * 16 + l15] = oacc[df][r];
    }
    __syncthreads();
    if (g == 0) {
        #pragma unroll
        for (int df = 0; df < 8; df++) {
            #pragma unroll
            for (int r = 0; r < 4; r++) {
                int row = w16 + quad * 4 + r;
                float o = (oacc[df][r] + sO[(quad * 4 + r) * 132 + df * 16 + l15]) * s_inv[row];
                out[((size_t)bh * 1024 + n0 + row) * 128 + df * 16 + l15] = o;
            }
        }
    }
}

__global__ __launch_bounds__(256) void scale_sc(float* __restrict__ scores, const float* __restrict__ wsInvd) {
    const int row = blockIdx.x;                   // 32768 rows
    const float iv = wsInvd[row];
    float4* p = reinterpret_cast<float4*>(scores + (size_t)row * 1024);
    float4 t = p[threadIdx.x];
    t.x *= iv; t.y *= iv; t.z *= iv; t.w *= iv;
    p[threadIdx.x] = t;
}

extern "C" void kernel_launch(void* const* d_in, const int* in_sizes, int n_in,
                              void* d_out, int out_size, void* d_ws, size_t ws_size,
                              hipStream_t stream) {
    const float* q   = (const float*)d_in[0];
    const float* k   = (const float*)d_in[1];
    const float* v   = (const float*)d_in[2];
    const float* c   = (const float*)d_in[3];
    const float* dq  = (const float*)d_in[4];
    const float* dk  = (const float*)d_in[5];
    const float* w_w = (const float*)d_in[6];
    const float* b_w = (const float*)d_in[7];
    const float* w_b = (const float*)d_in[8];
    const float* b_b = (const float*)d_in[9];
    float* out = (float*)d_out;
    char* ws = (char*)d_ws;
    unsigned short* wsK  = (unsigned short*)(ws + WS_K);
    unsigned short* wsVt = (unsigned short*)(ws + WS_VT);
    float* wsInvd = (float*)(ws + WS_INVD);
    float* wsCs   = (float*)(ws + WS_CS);

    hipLaunchKernelGGL(prep_k, dim3(512), dim3(256), 0, stream, k, wsK);
    hipLaunchKernelGGL(prep_v, dim3(512), dim3(256), 0, stream, v, wsVt);
    hipLaunchKernelGGL(prep_c, dim3(32),  dim3(256), 0, stream, c, wsCs);
    hipLaunchKernelGGL(sam_main, dim3(512), dim3(512), 0, stream,
                       q, dq, dk, w_w, b_w, w_b, b_b, wsK, wsVt, wsCs, wsInvd, out);
    hipLaunchKernelGGL(scale_sc, dim3(32768), dim3(256), 0, stream, out + OUT_ELEMS, wsInvd);
}

// Round 4
// 273.113 us; speedup vs baseline: 1.2305x; 1.0569x over previous
//
#include <hip/hip_runtime.h>

// RelativeSAMAttention: B=4,H=8,N=1024,DH=128. Outputs FP32: out[B,H,N,DH] ++ scores[B,H,N,N].
//
// Pipeline: prep_all (K->bf16 ws | V->bf16^T ws | cs per bh),
//   sam_main (QK^T + distmap once + rowsums + PV(unscaled) + bf16 P tile -> ws,
//             epilogue scales O by 1/detr, writes invd to ws),
//   rescale  (scores = fp32(bf16 P) * invd[row]; P read is Infinity-Cache-hot).
// Avoids R3's 402 MB fp32 score round-trip (write+read+write) -> 67 W + 67 R(L3) + 134 W.

typedef __attribute__((ext_vector_type(8))) short short8;
typedef __attribute__((ext_vector_type(4))) float f32x4;

#define OUT_ELEMS 4194304ull
#define WS_K      0ull           //  8388608 B bf16 K [bh][m][dh]
#define WS_VT     8388608ull     //  8388608 B bf16 V^T [bh][dh][m]
#define WS_P      16777216ull    // 67108864 B bf16 unscaled P [bh][n][m]
#define WS_INVD   83886080ull    //   131072 B fp32 invd[32*1024]
#define WS_CS     84017152ull    //      128 B fp32 cs[32]

__device__ __forceinline__ unsigned short f2bf(float f) {
    unsigned u = __builtin_bit_cast(unsigned, f);
    u += 0x7FFFu + ((u >> 16) & 1u);
    return (unsigned short)(u >> 16);
}
__device__ __forceinline__ float bf2f(unsigned short s) {
    unsigned u = ((unsigned)s) << 16;
    return __builtin_bit_cast(float, u);
}
__device__ __forceinline__ float softplus(float x) {
    return fmaxf(x, 0.f) + __logf(1.f + __expf(-fabsf(x)));
}

// ---------------- merged prep: blocks [0,512) K-convert, [512,1024) V-transpose, [1024,1056) cs ----
__global__ __launch_bounds__(256) void prep_all(
    const float* __restrict__ k, const float* __restrict__ v, const float* __restrict__ c,
    unsigned short* __restrict__ wsK, unsigned short* __restrict__ wsVt, float* __restrict__ wsCs)
{
    __shared__ unsigned short sT[64 * 132];
    const int blk = blockIdx.x, tid = threadIdx.x;
    if (blk < 512) {
        int t = blk * 256 + tid;
        for (int u = t; u < 524288; u += 131072) {
            float4 a = reinterpret_cast<const float4*>(k)[u * 2];
            float4 b = reinterpret_cast<const float4*>(k)[u * 2 + 1];
            short8 o;
            o[0]=(short)f2bf(a.x); o[1]=(short)f2bf(a.y); o[2]=(short)f2bf(a.z); o[3]=(short)f2bf(a.w);
            o[4]=(short)f2bf(b.x); o[5]=(short)f2bf(b.y); o[6]=(short)f2bf(b.z); o[7]=(short)f2bf(b.w);
            reinterpret_cast<short8*>(wsK)[u] = o;
        }
    } else if (blk < 1024) {
        const int vb = blk - 512;
        const int bh = vb >> 4, m0 = (vb & 15) * 64;
        const float* src = v + ((size_t)bh * 1024 + m0) * 128;
        for (int i = tid; i < 2048; i += 256) {
            int row = i >> 5, c4 = i & 31;
            float4 t = reinterpret_cast<const float4*>(src)[i];
            unsigned long long pk = (unsigned long long)f2bf(t.x)
                                  | ((unsigned long long)f2bf(t.y) << 16)
                                  | ((unsigned long long)f2bf(t.z) << 32)
                                  | ((unsigned long long)f2bf(t.w) << 48);
            *reinterpret_cast<unsigned long long*>(&sT[row * 132 + c4 * 4]) = pk;
        }
        __syncthreads();
        for (int u = tid; u < 2048; u += 256) {
            int dh = u >> 4, ms = u & 15;
            unsigned long long pk = (unsigned long long)sT[(ms*4+0)*132 + dh]
                                  | ((unsigned long long)sT[(ms*4+1)*132 + dh] << 16)
                                  | ((unsigned long long)sT[(ms*4+2)*132 + dh] << 32)
                                  | ((unsigned long long)sT[(ms*4+3)*132 + dh] << 48);
            *reinterpret_cast<unsigned long long*>(&wsVt[((size_t)bh * 128 + dh) * 1024 + m0 + ms * 4]) = pk;
        }
    } else {
        __shared__ float red[4];
        const int bh = blk - 1024;
        float p = 0.f;
        for (int i = tid; i < 1024; i += 256) p += softplus(c[(size_t)bh * 1024 + i]);
        p += __shfl_xor(p, 32, 64); p += __shfl_xor(p, 16, 64); p += __shfl_xor(p, 8, 64);
        p += __shfl_xor(p,  4, 64); p += __shfl_xor(p,  2, 64); p += __shfl_xor(p, 1, 64);
        if ((tid & 63) == 0) red[tid >> 6] = p;
        __syncthreads();
        if (tid == 0) wsCs[bh] = red[0] + red[1] + red[2] + red[3] + 1e-9f;
    }
}

// ---------------- main ----------------
__global__ __launch_bounds__(512, 4) void sam_main(
    const float* __restrict__ q, const float* __restrict__ dqp, const float* __restrict__ dkp,
    const float* __restrict__ w_w, const float* __restrict__ b_w,
    const float* __restrict__ w_b, const float* __restrict__ b_b,
    const unsigned short* __restrict__ wsK, const unsigned short* __restrict__ wsVt,
    const float* __restrict__ wsCs, float* __restrict__ wsInvd,
    unsigned short* __restrict__ wsP, float* __restrict__ out)
{
    __shared__ __align__(16) unsigned short sKall[2 * 8704];   // [g][64m][136]; aliases: Q stage, sP strips, sO merge
    __shared__ __align__(16) unsigned short sVtall[2 * 9216];  // [g][128dh][72]
    __shared__ float sdkall[2 * 256];                          // [g][4comp][64m]; aliased as rowsum buf at end
    __shared__ float s_inv[64];

    const int bid  = blockIdx.x;
    const int bh   = bid & 31;
    const int n0   = (bid >> 5) * 64;
    const int b    = bh >> 3;
    const int h    = bh & 7;
    const int tid  = threadIdx.x;
    const int lane = tid & 63;
    const int wave = tid >> 6;
    const int g    = wave >> 2;
    const int wl   = wave & 3;
    const int w16  = wl * 16;
    const int tg   = tid & 255;
    const int l15  = lane & 15;
    const int quad = lane >> 4;

    const float ww = w_w[h], bw = b_w[h], wb = w_b[h], bb = b_b[h];
    const float SCALE = 0.08838834764831845f;   // 1/sqrt(128)

    // ---- prologue: Q tile (fp32->bf16) into sKall, dq geometry, cs ----
    {
        const float* qbase = q + ((size_t)bh * 1024 + n0) * 128;
        for (int i = tid; i < 2048; i += 512) {
            int row = i >> 5, c4 = i & 31;
            float4 t = reinterpret_cast<const float4*>(qbase)[i];
            unsigned long long pk = (unsigned long long)f2bf(t.x)
                                  | ((unsigned long long)f2bf(t.y) << 16)
                                  | ((unsigned long long)f2bf(t.z) << 32)
                                  | ((unsigned long long)f2bf(t.w) << 48);
            *reinterpret_cast<unsigned long long*>(&sKall[row * 136 + c4 * 4]) = pk;
        }
    }
    float qx[4], qy[4], qz[4], qs[4];
    #pragma unroll
    for (int r = 0; r < 4; r++) {
        int nl = w16 + quad * 4 + r;
        float4 d4 = reinterpret_cast<const float4*>(dqp)[(size_t)b * 1024 + n0 + nl];
        qx[r] = d4.x; qy[r] = d4.y; qz[r] = d4.z;
        qs[r] = d4.x*d4.x + d4.y*d4.y + d4.z*d4.z;
    }
    const float cs = wsCs[bh];
    __syncthreads();
    short8 afr[4];
    {
        const unsigned short* aq = &sKall[(w16 + l15) * 136];
        #pragma unroll
        for (int ks = 0; ks < 4; ks++)
            afr[ks] = *reinterpret_cast<const short8*>(aq + ks * 32 + quad * 8);
    }
    __syncthreads();   // sKall free for m-tiles

    f32x4 oacc[8];
    #pragma unroll
    for (int i = 0; i < 8; i++) oacc[i] = {0.f, 0.f, 0.f, 0.f};
    float rs[4] = {0.f, 0.f, 0.f, 0.f};

    unsigned short* sKg  = sKall  + g * 8704;
    unsigned short* sVtg = sVtall + g * 9216;
    unsigned short* sP   = sKg + wl * 1152;                // 16 rows x 72 shorts, wave-private
    float* sdkg = sdkall + g * 256;

    for (int t8 = 0; t8 < 8; t8++) {
        const int m0 = (t8 * 2 + g) * 64;
        // ---- group-local staging (bf16 ws -> LDS; pure copies) ----
        for (int i = tg; i < 1024; i += 256) {             // sK: 64 rows x 16 short8
            int row = i >> 4, seg = i & 15;
            short8 d = *reinterpret_cast<const short8*>(wsK + ((size_t)bh * 1024 + m0 + row) * 128 + seg * 8);
            *reinterpret_cast<short8*>(&sKg[row * 136 + seg * 8]) = d;
        }
        for (int i = tg; i < 1024; i += 256) {             // sVt: 128 dh x 8 short8
            int dh = i >> 3, seg = i & 7;
            short8 d = *reinterpret_cast<const short8*>(wsVt + ((size_t)bh * 128 + dh) * 1024 + m0 + seg * 8);
            *reinterpret_cast<short8*>(&sVtg[dh * 72 + seg * 8]) = d;
        }
        if (tg < 64) {
            float4 d4 = reinterpret_cast<const float4*>(dkp)[(size_t)b * 1024 + m0 + tg];
            sdkg[tg] = d4.x; sdkg[64 + tg] = d4.y; sdkg[128 + tg] = d4.z;
            sdkg[192 + tg] = d4.x*d4.x + d4.y*d4.y + d4.z*d4.z;
        }
        __syncthreads();

        // ---- QK^T into registers (so sKg can be reused as sP) ----
        f32x4 cacc[4];
        #pragma unroll
        for (int mf = 0; mf < 4; mf++) {
            cacc[mf] = {0.f, 0.f, 0.f, 0.f};
            const unsigned short* bq = &sKg[(mf * 16 + l15) * 136];
            #pragma unroll
            for (int ks = 0; ks < 4; ks++) {
                short8 bfr = *reinterpret_cast<const short8*>(bq + ks * 32 + quad * 8);
                cacc[mf] = __builtin_amdgcn_mfma_f32_16x16x32_bf16(afr[ks], bfr, cacc[mf], 0, 0, 0);
            }
        }
        __syncthreads();   // all sKg reads done; region becomes sP strips

        // ---- distmap ONCE: rowsums + bf16 sP ----
        #pragma unroll
        for (int mf = 0; mf < 4; mf++) {
            const int mloc = mf * 16 + l15;
            const float kx = sdkg[mloc], ky = sdkg[64 + mloc], kz = sdkg[128 + mloc], ksq = sdkg[192 + mloc];
            #pragma unroll
            for (int r = 0; r < 4; r++) {
                float dist = qs[r] + ksq - 2.f * (qx[r]*kx + qy[r]*ky + qz[r]*kz);
                float aw = softplus(-(dist * ww + bw));
                float ab = dist * wb + bb;
                float val = fmaxf(cacc[mf][r] * SCALE * aw + ab, 0.f);
                rs[r] += val;
                sP[(quad * 4 + r) * 72 + mf * 16 + l15] = f2bf(val);
            }
        }
        // ---- PV with unscaled P (wave-private sP: no barrier, lgkm only) ----
        #pragma unroll
        for (int ks2 = 0; ks2 < 2; ks2++) {
            short8 pfr = *reinterpret_cast<const short8*>(&sP[l15 * 72 + ks2 * 32 + quad * 8]);
            #pragma unroll
            for (int df = 0; df < 8; df++) {
                short8 vfr = *reinterpret_cast<const short8*>(&sVtg[(df * 16 + l15) * 72 + ks2 * 32 + quad * 8]);
                oacc[df] = __builtin_amdgcn_mfma_f32_16x16x32_bf16(pfr, vfr, oacc[df], 0, 0, 0);
            }
        }
        // ---- repack own sP strip -> ws (bf16, 128B-contiguous row chunks) ----
        {
            unsigned short* dst = wsP + ((size_t)bh * 1024 + n0 + w16) * 1024 + m0;
            #pragma unroll
            for (int half = 0; half < 2; half++) {
                int u = half * 64 + lane;
                int row = u >> 3, seg = u & 7;
                short8 d = *reinterpret_cast<const short8*>(&sP[row * 72 + seg * 8]);
                *reinterpret_cast<short8*>(dst + (size_t)row * 1024 + seg * 8) = d;
            }
        }
        __syncthreads();   // sP/sVtg reads done before next restage
    }

    // ---- merge group rowsums -> invd ----
    #pragma unroll
    for (int r = 0; r < 4; r++) {
        float t = rs[r];
        t += __shfl_xor(t, 1, 64); t += __shfl_xor(t, 2, 64);
        t += __shfl_xor(t, 4, 64); t += __shfl_xor(t, 8, 64);
        if (l15 == 0) sdkall[g * 256 + w16 + quad * 4 + r] = t;
    }
    __syncthreads();
    if (tid < 64) {
        float iv = 1.f / (sdkall[tid] + sdkall[256 + tid] + cs);
        s_inv[tid] = iv;
        wsInvd[(size_t)bh * 1024 + n0 + tid] = iv;
    }
    __syncthreads();

    // ---- merge group O-partials, scale, store ----
    float* sO = reinterpret_cast<float*>(sKall) + wl * 2112;      // 16 rows x 132 floats
    if (g == 1) {
        #pragma unroll
        for (int df = 0; df < 8; df++)
            #pragma unroll
            for (int r = 0; r < 4; r++)
                sO[(quad * 4 + r) * 132 + df * 16 + l15] = oacc[df][r];
    }
    __syncthreads();
    if (g == 0) {
        #pragma unroll
        for (int df = 0; df < 8; df++) {
            #pragma unroll
            for (int r = 0; r < 4; r++) {
                int row = w16 + quad * 4 + r;
                float o = (oacc[df][r] + sO[(quad * 4 + r) * 132 + df * 16 + l15]) * s_inv[row];
                out[((size_t)bh * 1024 + n0 + row) * 128 + df * 16 + l15] = o;
            }
        }
    }
}

// ---------------- rescale: scores = fp32(bf16 P) * invd[row] ----------------
__global__ __launch_bounds__(256) void rescale(
    const unsigned short* __restrict__ wsP, const float* __restrict__ wsInvd,
    float* __restrict__ scores)
{
    const int row = blockIdx.x;                   // 32768 rows
    const float iv = wsInvd[row];
    const unsigned long long d = *reinterpret_cast<const unsigned long long*>(
        wsP + (size_t)row * 1024 + threadIdx.x * 4);
    float4 o;
    o.x = bf2f((unsigned short)(d       & 0xFFFF)) * iv;
    o.y = bf2f((unsigned short)((d>>16) & 0xFFFF)) * iv;
    o.z = bf2f((unsigned short)((d>>32) & 0xFFFF)) * iv;
    o.w = bf2f((unsigned short)((d>>48) & 0xFFFF)) * iv;
    reinterpret_cast<float4*>(scores + (size_t)row * 1024)[threadIdx.x] = o;
}

extern "C" void kernel_launch(void* const* d_in, const int* in_sizes, int n_in,
                              void* d_out, int out_size, void* d_ws, size_t ws_size,
                              hipStream_t stream) {
    const float* q   = (const float*)d_in[0];
    const float* k   = (const float*)d_in[1];
    const float* v   = (const float*)d_in[2];
    const float* c   = (const float*)d_in[3];
    const float* dq  = (const float*)d_in[4];
    const float* dk  = (const float*)d_in[5];
    const float* w_w = (const float*)d_in[6];
    const float* b_w = (const float*)d_in[7];
    const float* w_b = (const float*)d_in[8];
    const float* b_b = (const float*)d_in[9];
    float* out = (float*)d_out;
    char* ws = (char*)d_ws;
    unsigned short* wsK  = (unsigned short*)(ws + WS_K);
    unsigned short* wsVt = (unsigned short*)(ws + WS_VT);
    unsigned short* wsP  = (unsigned short*)(ws + WS_P);
    float* wsInvd = (float*)(ws + WS_INVD);
    float* wsCs   = (float*)(ws + WS_CS);

    hipLaunchKernelGGL(prep_all, dim3(1056), dim3(256), 0, stream, k, v, c, wsK, wsVt, wsCs);
    hipLaunchKernelGGL(sam_main, dim3(512), dim3(512), 0, stream,
                       q, dq, dk, w_w, b_w, w_b, b_b, wsK, wsVt, wsCs, wsInvd, wsP, out);
    hipLaunchKernelGGL(rescale, dim3(32768), dim3(256), 0, stream, wsP, wsInvd, out + OUT_ELEMS);
}

// Round 5
// 268.403 us; speedup vs baseline: 1.2521x; 1.0175x over previous
//
#include <hip/hip_runtime.h>

// RelativeSAMAttention: B=4,H=8,N=1024,DH=128. Outputs FP32: out[B,H,N,DH] ++ scores[B,H,N,N].
//
// Pipeline: prep_all (K->bf16 ws | V->bf16^T ws | cs per bh),
//   sam_main: block-local TWO-PASS over m:
//     pass 1: QK^T + distmap -> rowsums only (no stores) -> invd (block-local; each block owns rows)
//     pass 2: recompute QK^T + distmap (L2-hot bf16 K), p = val*invd -> fp32 scores written ONCE,
//             scaled bf16 P -> wave-private LDS strip -> PV MFMA -> out (no extra scaling).
//   Kills R4's P workspace round-trip (67 MB W + 67 MB R) and the rescale kernel entirely.
// 512 blocks x 512 thr (8 waves; groups g=0/1 split m into alternating 64-wide tiles),
// LDS ~74 KB + __launch_bounds__(512,4) -> 2 blocks/CU.

typedef __attribute__((ext_vector_type(8))) short short8;
typedef __attribute__((ext_vector_type(4))) float f32x4;

#define OUT_ELEMS 4194304ull
#define WS_K      0ull           //  8388608 B bf16 K [bh][m][dh]
#define WS_VT     8388608ull     //  8388608 B bf16 V^T [bh][dh][m]
#define WS_CS     16777216ull    //      128 B fp32 cs[32]

__device__ __forceinline__ unsigned short f2bf(float f) {
    unsigned u = __builtin_bit_cast(unsigned, f);
    u += 0x7FFFu + ((u >> 16) & 1u);
    return (unsigned short)(u >> 16);
}
__device__ __forceinline__ float softplus(float x) {
    return fmaxf(x, 0.f) + __logf(1.f + __expf(-fabsf(x)));
}

// ---------------- merged prep: blocks [0,512) K-convert, [512,1024) V-transpose, [1024,1056) cs ----
__global__ __launch_bounds__(256) void prep_all(
    const float* __restrict__ k, const float* __restrict__ v, const float* __restrict__ c,
    unsigned short* __restrict__ wsK, unsigned short* __restrict__ wsVt, float* __restrict__ wsCs)
{
    __shared__ unsigned short sT[64 * 132];
    const int blk = blockIdx.x, tid = threadIdx.x;
    if (blk < 512) {
        int t = blk * 256 + tid;
        for (int u = t; u < 524288; u += 131072) {
            float4 a = reinterpret_cast<const float4*>(k)[u * 2];
            float4 b = reinterpret_cast<const float4*>(k)[u * 2 + 1];
            short8 o;
            o[0]=(short)f2bf(a.x); o[1]=(short)f2bf(a.y); o[2]=(short)f2bf(a.z); o[3]=(short)f2bf(a.w);
            o[4]=(short)f2bf(b.x); o[5]=(short)f2bf(b.y); o[6]=(short)f2bf(b.z); o[7]=(short)f2bf(b.w);
            reinterpret_cast<short8*>(wsK)[u] = o;
        }
    } else if (blk < 1024) {
        const int vb = blk - 512;
        const int bh = vb >> 4, m0 = (vb & 15) * 64;
        const float* src = v + ((size_t)bh * 1024 + m0) * 128;
        for (int i = tid; i < 2048; i += 256) {
            int row = i >> 5, c4 = i & 31;
            float4 t = reinterpret_cast<const float4*>(src)[i];
            unsigned long long pk = (unsigned long long)f2bf(t.x)
                                  | ((unsigned long long)f2bf(t.y) << 16)
                                  | ((unsigned long long)f2bf(t.z) << 32)
                                  | ((unsigned long long)f2bf(t.w) << 48);
            *reinterpret_cast<unsigned long long*>(&sT[row * 132 + c4 * 4]) = pk;
        }
        __syncthreads();
        for (int u = tid; u < 2048; u += 256) {
            int dh = u >> 4, ms = u & 15;
            unsigned long long pk = (unsigned long long)sT[(ms*4+0)*132 + dh]
                                  | ((unsigned long long)sT[(ms*4+1)*132 + dh] << 16)
                                  | ((unsigned long long)sT[(ms*4+2)*132 + dh] << 32)
                                  | ((unsigned long long)sT[(ms*4+3)*132 + dh] << 48);
            *reinterpret_cast<unsigned long long*>(&wsVt[((size_t)bh * 128 + dh) * 1024 + m0 + ms * 4]) = pk;
        }
    } else {
        __shared__ float red[4];
        const int bh = blk - 1024;
        float p = 0.f;
        for (int i = tid; i < 1024; i += 256) p += softplus(c[(size_t)bh * 1024 + i]);
        p += __shfl_xor(p, 32, 64); p += __shfl_xor(p, 16, 64); p += __shfl_xor(p, 8, 64);
        p += __shfl_xor(p,  4, 64); p += __shfl_xor(p,  2, 64); p += __shfl_xor(p, 1, 64);
        if ((tid & 63) == 0) red[tid >> 6] = p;
        __syncthreads();
        if (tid == 0) wsCs[bh] = red[0] + red[1] + red[2] + red[3] + 1e-9f;
    }
}

// ---------------- main: two-pass ----------------
__global__ __launch_bounds__(512, 4) void sam_main(
    const float* __restrict__ q, const float* __restrict__ dqp, const float* __restrict__ dkp,
    const float* __restrict__ w_w, const float* __restrict__ b_w,
    const float* __restrict__ w_b, const float* __restrict__ b_b,
    const unsigned short* __restrict__ wsK, const unsigned short* __restrict__ wsVt,
    const float* __restrict__ wsCs, float* __restrict__ out)
{
    __shared__ __align__(16) unsigned short sKall[2 * 8704];   // [g][64m][136]; aliases: Q stage, sP strips, sO merge
    __shared__ __align__(16) unsigned short sVtall[2 * 9216];  // [g][128dh][72]
    __shared__ float sdkall[2 * 256];                          // [g][4comp][64m]; aliased as rowsum buf
    __shared__ float s_inv[64];

    const int bid  = blockIdx.x;
    const int bh   = bid & 31;
    const int n0   = (bid >> 5) * 64;
    const int b    = bh >> 3;
    const int h    = bh & 7;
    const int tid  = threadIdx.x;
    const int lane = tid & 63;
    const int wave = tid >> 6;
    const int g    = wave >> 2;
    const int wl   = wave & 3;
    const int w16  = wl * 16;
    const int tg   = tid & 255;
    const int l15  = lane & 15;
    const int quad = lane >> 4;

    const float ww = w_w[h], bw = b_w[h], wb = w_b[h], bb = b_b[h];
    const float SCALE = 0.08838834764831845f;   // 1/sqrt(128)

    // ---- prologue: Q tile (fp32->bf16) into sKall, dq geometry, cs ----
    {
        const float* qbase = q + ((size_t)bh * 1024 + n0) * 128;
        for (int i = tid; i < 2048; i += 512) {
            int row = i >> 5, c4 = i & 31;
            float4 t = reinterpret_cast<const float4*>(qbase)[i];
            unsigned long long pk = (unsigned long long)f2bf(t.x)
                                  | ((unsigned long long)f2bf(t.y) << 16)
                                  | ((unsigned long long)f2bf(t.z) << 32)
                                  | ((unsigned long long)f2bf(t.w) << 48);
            *reinterpret_cast<unsigned long long*>(&sKall[row * 136 + c4 * 4]) = pk;
        }
    }
    float qx[4], qy[4], qz[4], qs[4];
    #pragma unroll
    for (int r = 0; r < 4; r++) {
        int nl = w16 + quad * 4 + r;
        float4 d4 = reinterpret_cast<const float4*>(dqp)[(size_t)b * 1024 + n0 + nl];
        qx[r] = d4.x; qy[r] = d4.y; qz[r] = d4.z;
        qs[r] = d4.x*d4.x + d4.y*d4.y + d4.z*d4.z;
    }
    const float cs = wsCs[bh];
    __syncthreads();
    short8 afr[4];
    {
        const unsigned short* aq = &sKall[(w16 + l15) * 136];
        #pragma unroll
        for (int ks = 0; ks < 4; ks++)
            afr[ks] = *reinterpret_cast<const short8*>(aq + ks * 32 + quad * 8);
    }
    __syncthreads();   // sKall free for m-tiles

    unsigned short* sKg  = sKall  + g * 8704;
    unsigned short* sVtg = sVtall + g * 9216;
    unsigned short* sP   = sKg + wl * 1152;                // 16 rows x 72 shorts, wave-private
    float* sdkg = sdkall + g * 256;

    // ================= PASS 1: rowsums only =================
    float rs[4] = {0.f, 0.f, 0.f, 0.f};
    for (int t8 = 0; t8 < 8; t8++) {
        const int m0 = (t8 * 2 + g) * 64;
        for (int i = tg; i < 1024; i += 256) {             // sK: 64 rows x 16 short8
            int row = i >> 4, seg = i & 15;
            short8 d = *reinterpret_cast<const short8*>(wsK + ((size_t)bh * 1024 + m0 + row) * 128 + seg * 8);
            *reinterpret_cast<short8*>(&sKg[row * 136 + seg * 8]) = d;
        }
        if (tg < 64) {
            float4 d4 = reinterpret_cast<const float4*>(dkp)[(size_t)b * 1024 + m0 + tg];
            sdkg[tg] = d4.x; sdkg[64 + tg] = d4.y; sdkg[128 + tg] = d4.z;
            sdkg[192 + tg] = d4.x*d4.x + d4.y*d4.y + d4.z*d4.z;
        }
        __syncthreads();

        f32x4 cacc[4];
        #pragma unroll
        for (int mf = 0; mf < 4; mf++) {
            cacc[mf] = {0.f, 0.f, 0.f, 0.f};
            const unsigned short* bq = &sKg[(mf * 16 + l15) * 136];
            #pragma unroll
            for (int ks = 0; ks < 4; ks++) {
                short8 bfr = *reinterpret_cast<const short8*>(bq + ks * 32 + quad * 8);
                cacc[mf] = __builtin_amdgcn_mfma_f32_16x16x32_bf16(afr[ks], bfr, cacc[mf], 0, 0, 0);
            }
        }
        #pragma unroll
        for (int mf = 0; mf < 4; mf++) {
            const int mloc = mf * 16 + l15;
            const float kx = sdkg[mloc], ky = sdkg[64 + mloc], kz = sdkg[128 + mloc], ksq = sdkg[192 + mloc];
            #pragma unroll
            for (int r = 0; r < 4; r++) {
                float dist = qs[r] + ksq - 2.f * (qx[r]*kx + qy[r]*ky + qz[r]*kz);
                float aw = softplus(-(dist * ww + bw));
                float ab = dist * wb + bb;
                rs[r] += fmaxf(cacc[mf][r] * SCALE * aw + ab, 0.f);
            }
        }
        __syncthreads();   // sKg/sdkg reads done before next restage
    }

    // ---- merge group rowsums -> invd (block-local; sdkall region is free here) ----
    #pragma unroll
    for (int r = 0; r < 4; r++) {
        float t = rs[r];
        t += __shfl_xor(t, 1, 64); t += __shfl_xor(t, 2, 64);
        t += __shfl_xor(t, 4, 64); t += __shfl_xor(t, 8, 64);
        if (l15 == 0) sdkall[g * 256 + w16 + quad * 4 + r] = t;
    }
    __syncthreads();
    if (tid < 64) s_inv[tid] = 1.f / (sdkall[tid] + sdkall[256 + tid] + cs);
    __syncthreads();

    float inv4[4];
    #pragma unroll
    for (int r = 0; r < 4; r++) inv4[r] = s_inv[w16 + quad * 4 + r];

    // ================= PASS 2: recompute, scale, store scores, PV =================
    f32x4 oacc[8];
    #pragma unroll
    for (int i = 0; i < 8; i++) oacc[i] = {0.f, 0.f, 0.f, 0.f};
    float* scb = out + OUT_ELEMS + ((size_t)bh << 20);

    for (int t8 = 0; t8 < 8; t8++) {
        const int m0 = (t8 * 2 + g) * 64;
        for (int i = tg; i < 1024; i += 256) {             // sK (L2-hot re-read)
            int row = i >> 4, seg = i & 15;
            short8 d = *reinterpret_cast<const short8*>(wsK + ((size_t)bh * 1024 + m0 + row) * 128 + seg * 8);
            *reinterpret_cast<short8*>(&sKg[row * 136 + seg * 8]) = d;
        }
        for (int i = tg; i < 1024; i += 256) {             // sVt: 128 dh x 8 short8
            int dh = i >> 3, seg = i & 7;
            short8 d = *reinterpret_cast<const short8*>(wsVt + ((size_t)bh * 128 + dh) * 1024 + m0 + seg * 8);
            *reinterpret_cast<short8*>(&sVtg[dh * 72 + seg * 8]) = d;
        }
        if (tg < 64) {
            float4 d4 = reinterpret_cast<const float4*>(dkp)[(size_t)b * 1024 + m0 + tg];
            sdkg[tg] = d4.x; sdkg[64 + tg] = d4.y; sdkg[128 + tg] = d4.z;
            sdkg[192 + tg] = d4.x*d4.x + d4.y*d4.y + d4.z*d4.z;
        }
        __syncthreads();

        f32x4 cacc[4];
        #pragma unroll
        for (int mf = 0; mf < 4; mf++) {
            cacc[mf] = {0.f, 0.f, 0.f, 0.f};
            const unsigned short* bq = &sKg[(mf * 16 + l15) * 136];
            #pragma unroll
            for (int ks = 0; ks < 4; ks++) {
                short8 bfr = *reinterpret_cast<const short8*>(bq + ks * 32 + quad * 8);
                cacc[mf] = __builtin_amdgcn_mfma_f32_16x16x32_bf16(afr[ks], bfr, cacc[mf], 0, 0, 0);
            }
        }
        __syncthreads();   // all sKg reads done; region becomes sP strips

        #pragma unroll
        for (int mf = 0; mf < 4; mf++) {
            const int mloc = mf * 16 + l15;
            const float kx = sdkg[mloc], ky = sdkg[64 + mloc], kz = sdkg[128 + mloc], ksq = sdkg[192 + mloc];
            #pragma unroll
            for (int r = 0; r < 4; r++) {
                float dist = qs[r] + ksq - 2.f * (qx[r]*kx + qy[r]*ky + qz[r]*kz);
                float aw = softplus(-(dist * ww + bw));
                float ab = dist * wb + bb;
                float val = fmaxf(cacc[mf][r] * SCALE * aw + ab, 0.f);
                float p   = val * inv4[r];                 // final scaled score
                sP[(quad * 4 + r) * 72 + mf * 16 + l15] = f2bf(p);
                scb[(size_t)(n0 + w16 + quad * 4 + r) * 1024 + m0 + mf * 16 + l15] = p;
            }
        }
        // PV with scaled P (wave-private sP: lgkm wait only, no barrier)
        #pragma unroll
        for (int ks2 = 0; ks2 < 2; ks2++) {
            short8 pfr = *reinterpret_cast<const short8*>(&sP[l15 * 72 + ks2 * 32 + quad * 8]);
            #pragma unroll
            for (int df = 0; df < 8; df++) {
                short8 vfr = *reinterpret_cast<const short8*>(&sVtg[(df * 16 + l15) * 72 + ks2 * 32 + quad * 8]);
                oacc[df] = __builtin_amdgcn_mfma_f32_16x16x32_bf16(pfr, vfr, oacc[df], 0, 0, 0);
            }
        }
        __syncthreads();   // sP/sVtg/sdkg reads done before next restage
    }

    // ---- merge group O-partials (already invd-scaled via P), store ----
    float* sO = reinterpret_cast<float*>(sKall) + wl * 2112;      // 16 rows x 132 floats
    if (g == 1) {
        #pragma unroll
        for (int df = 0; df < 8; df++)
            #pragma unroll
            for (int r = 0; r < 4; r++)
                sO[(quad * 4 + r) * 132 + df * 16 + l15] = oacc[df][r];
    }
    __syncthreads();
    if (g == 0) {
        #pragma unroll
        for (int df = 0; df < 8; df++) {
            #pragma unroll
            for (int r = 0; r < 4; r++) {
                int row = w16 + quad * 4 + r;
                float o = oacc[df][r] + sO[(quad * 4 + r) * 132 + df * 16 + l15];
                out[((size_t)bh * 1024 + n0 + row) * 128 + df * 16 + l15] = o;
            }
        }
    }
}

extern "C" void kernel_launch(void* const* d_in, const int* in_sizes, int n_in,
                              void* d_out, int out_size, void* d_ws, size_t ws_size,
                              hipStream_t stream) {
    const float* q   = (const float*)d_in[0];
    const float* k   = (const float*)d_in[1];
    const float* v   = (const float*)d_in[2];
    const float* c   = (const float*)d_in[3];
    const float* dq  = (const float*)d_in[4];
    const float* dk  = (const float*)d_in[5];
    const float* w_w = (const float*)d_in[6];
    const float* b_w = (const float*)d_in[7];
    const float* w_b = (const float*)d_in[8];
    const float* b_b = (const float*)d_in[9];
    float* out = (float*)d_out;
    char* ws = (char*)d_ws;
    unsigned short* wsK  = (unsigned short*)(ws + WS_K);
    unsigned short* wsVt = (unsigned short*)(ws + WS_VT);
    float* wsCs   = (float*)(ws + WS_CS);

    hipLaunchKernelGGL(prep_all, dim3(1056), dim3(256), 0, stream, k, v, c, wsK, wsVt, wsCs);
    hipLaunchKernelGGL(sam_main, dim3(512), dim3(512), 0, stream,
                       q, dq, dk, w_w, b_w, w_b, b_b, wsK, wsVt, wsCs, out);
}